// Round 1
// baseline (52.968 us; speedup 1.0000x reference)
//
#include <hip/hip_runtime.h>
#include <hip/hip_bf16.h>

// Chamfer distance, B=2, N=M=8192, 3-D fp32 points.
// Strategy: brute-force NN, fp32 VALU (no fp32 MFMA on CDNA4).
// Pass 1: for each (batch, dir, query) compute partial min-dist^2 over a
//         target chunk staged in LDS; 4 queries per thread in registers so one
//         ds_read_b128 feeds 16 FMA/min ops.
// Pass 2: combine partial mins, sum, scale by 80^2 / (B*8192).

#define NQ 8192          // queries per (batch,dir)
#define QCHUNK 1024      // queries per block (256 threads x QPT)
#define QPT 4            // queries per thread
#define TCHUNK 512       // targets per block (LDS staged)
#define TC 16            // target chunks (NQ / TCHUNK)
#define SCALE (6400.0f / 16384.0f)  // 80^2 / (B * 8192)

__global__ __launch_bounds__(256) void chamfer_nn_kernel(
    const float* __restrict__ pred, const float* __restrict__ gt,
    float* __restrict__ ws) {
  const int tc = blockIdx.x;  // target chunk 0..TC-1
  const int qc = blockIdx.y;  // query chunk 0..7
  const int z  = blockIdx.z;  // 0..3 : batch = z>>1, dir = z&1
  const int b = z >> 1, dir = z & 1;

  const float* qptr = (dir == 0 ? pred : gt) + (size_t)b * NQ * 3;
  const float* tptr = (dir == 0 ? gt : pred) + (size_t)b * NQ * 3;

  __shared__ float4 ldsT[TCHUNK];  // 8 KB

  const int t = threadIdx.x;

  // Stage target chunk into LDS as float4 {x,y,z,0}
  const float* tb = tptr + (size_t)tc * TCHUNK * 3;
  for (int j = t; j < TCHUNK; j += 256) {
    ldsT[j] = make_float4(tb[j * 3], tb[j * 3 + 1], tb[j * 3 + 2], 0.0f);
  }
  __syncthreads();

  // Load QPT queries into registers
  float qx[QPT], qy[QPT], qz[QPT], m[QPT];
  const int qbase = qc * QCHUNK;
#pragma unroll
  for (int q = 0; q < QPT; ++q) {
    const int qi = qbase + t + 256 * q;
    qx[q] = qptr[qi * 3];
    qy[q] = qptr[qi * 3 + 1];
    qz[q] = qptr[qi * 3 + 2];
    m[q] = 3.4e38f;
  }

  // Scan all staged targets
#pragma unroll 4
  for (int j = 0; j < TCHUNK; ++j) {
    const float4 tp = ldsT[j];
#pragma unroll
    for (int q = 0; q < QPT; ++q) {
      const float dx = qx[q] - tp.x;
      const float dy = qy[q] - tp.y;
      const float dz = qz[q] - tp.z;
      const float d = fmaf(dz, dz, fmaf(dy, dy, dx * dx));
      m[q] = fminf(m[q], d);
    }
  }

  // Write partial mins: ws[g * TC + tc], g = global query id
#pragma unroll
  for (int q = 0; q < QPT; ++q) {
    const int g = z * NQ + qbase + t + 256 * q;
    ws[(size_t)g * TC + tc] = m[q];
  }
}

__global__ __launch_bounds__(256) void chamfer_reduce_kernel(
    const float* __restrict__ ws, float* __restrict__ out) {
  // 4*NQ = 32768 queries total; 64 blocks x 512 queries each.
  const int g0 = blockIdx.x * 512;
  float sum = 0.0f;
  for (int g = g0 + (int)threadIdx.x; g < g0 + 512; g += 256) {
    const float4* p = (const float4*)(ws + (size_t)g * TC);
    float mn = 3.4e38f;
#pragma unroll
    for (int k = 0; k < TC / 4; ++k) {
      const float4 a = p[k];
      mn = fminf(mn, fminf(fminf(a.x, a.y), fminf(a.z, a.w)));
    }
    sum += mn;
  }
  // wave reduce (64 lanes)
#pragma unroll
  for (int off = 32; off > 0; off >>= 1) sum += __shfl_down(sum, off);
  __shared__ float red[4];
  const int lane = threadIdx.x & 63;
  const int wave = threadIdx.x >> 6;
  if (lane == 0) red[wave] = sum;
  __syncthreads();
  if (threadIdx.x == 0) {
    const float total = red[0] + red[1] + red[2] + red[3];
    atomicAdd(out, total * SCALE);
  }
}

extern "C" void kernel_launch(void* const* d_in, const int* in_sizes, int n_in,
                              void* d_out, int out_size, void* d_ws, size_t ws_size,
                              hipStream_t stream) {
  const float* pred = (const float*)d_in[0];
  const float* gt = (const float*)d_in[1];
  float* out = (float*)d_out;
  float* ws = (float*)d_ws;  // needs 4*NQ*TC*4 = 2 MB

  hipMemsetAsync(d_out, 0, sizeof(float), stream);

  dim3 grid1(TC, NQ / QCHUNK, 4);
  chamfer_nn_kernel<<<grid1, 256, 0, stream>>>(pred, gt, ws);

  chamfer_reduce_kernel<<<64, 256, 0, stream>>>(ws, out);
}

// Round 2
// 46.735 us; speedup vs baseline: 1.1334x; 1.1334x over previous
//
#include <hip/hip_runtime.h>
#include <hip/hip_bf16.h>

// Chamfer distance, B=2, N=M=8192, 3-D fp32 points. Pure fp32-VALU brute force.
//
// R2 changes vs R1 (48.4us nn kernel, VALUBusy 90%):
//  - Expanded distance: d2 = q.(-2t) + |t|^2 + |q|^2. LDS holds {-2t, |t|^2},
//    |q|^2 added in pass 2. Inner loop = 3 FMA + min per pair; two targets per
//    min step -> fminf(fminf(m,d0),d1) fusable to v_min3 => ~3.5 ops/pair
//    (was 7: 3 sub + mul + 2 fma + min).
//  - QPT 4->8: one ds_read_b128 feeds 8 queries; 8 independent min chains.
//  - TC 16->64: 1024 blocks = 4 blocks/CU = 4 waves/SIMD for latency hiding.
//  - ws transposed to [tc][query]: coalesced 256B wave stores (R1 wrote 16MiB
//    for 2MiB useful due to 64B-stride lane writes).

#define NQ 8192
#define QPT 8
#define QCHUNK 2048      // 256 threads * QPT
#define NQC 4            // NQ / QCHUNK
#define TOTQ 32768       // 4 * NQ  (batch x direction x query)
#define SCALE (6400.0f / 16384.0f)  // 80^2 / (B * 8192)

template <int TC>
__global__ __launch_bounds__(256) void chamfer_nn_kernel(
    const float* __restrict__ pred, const float* __restrict__ gt,
    float* __restrict__ ws) {
  constexpr int TCHUNK = NQ / TC;
  const int tc = blockIdx.x;  // target chunk
  const int qc = blockIdx.y;  // query chunk
  const int z  = blockIdx.z;  // 0..3 : batch = z>>1, dir = z&1
  const int b = z >> 1, dir = z & 1;

  const float* qptr = (dir == 0 ? pred : gt) + (size_t)b * NQ * 3;
  const float* tptr = (dir == 0 ? gt : pred) + (size_t)b * NQ * 3;

  __shared__ float4 ldsT[TCHUNK];  // {-2tx, -2ty, -2tz, |t|^2}

  const int t = threadIdx.x;

  const float* tb = tptr + (size_t)tc * TCHUNK * 3;
  for (int j = t; j < TCHUNK; j += 256) {
    const float tx = tb[j * 3], ty = tb[j * 3 + 1], tz = tb[j * 3 + 2];
    ldsT[j] = make_float4(-2.0f * tx, -2.0f * ty, -2.0f * tz,
                          fmaf(tx, tx, fmaf(ty, ty, tz * tz)));
  }
  __syncthreads();

  float qx[QPT], qy[QPT], qz[QPT], m[QPT];
  const int qbase = qc * QCHUNK + t;
#pragma unroll
  for (int q = 0; q < QPT; ++q) {
    const int qi = qbase + 256 * q;
    qx[q] = qptr[qi * 3];
    qy[q] = qptr[qi * 3 + 1];
    qz[q] = qptr[qi * 3 + 2];
    m[q] = 3.4e38f;
  }

#pragma unroll 2
  for (int j = 0; j < TCHUNK; j += 2) {
    const float4 t0 = ldsT[j];
    const float4 t1 = ldsT[j + 1];
#pragma unroll
    for (int q = 0; q < QPT; ++q) {
      const float d0 = fmaf(qz[q], t0.z, fmaf(qy[q], t0.y, fmaf(qx[q], t0.x, t0.w)));
      const float d1 = fmaf(qz[q], t1.z, fmaf(qy[q], t1.y, fmaf(qx[q], t1.x, t1.w)));
      m[q] = fminf(fminf(m[q], d0), d1);  // -> v_min3_f32
    }
  }

  // Transposed partial-min layout: ws[tc][g] -> coalesced wave stores.
#pragma unroll
  for (int q = 0; q < QPT; ++q) {
    const int g = z * NQ + qbase + 256 * q;
    ws[(size_t)tc * TOTQ + g] = m[q];
  }
}

template <int TC>
__global__ __launch_bounds__(256) void chamfer_reduce_kernel(
    const float* __restrict__ pred, const float* __restrict__ gt,
    const float* __restrict__ ws, float* __restrict__ out) {
  const int g = blockIdx.x * 256 + (int)threadIdx.x;  // 128 blocks x 256
  const int z = g >> 13, qi = g & 8191;
  const int b = z >> 1, dir = z & 1;
  const float* qptr = (dir == 0 ? pred : gt) + (size_t)b * NQ * 3;

  const float x = qptr[qi * 3], y = qptr[qi * 3 + 1], w = qptr[qi * 3 + 2];
  const float q2 = fmaf(x, x, fmaf(y, y, w * w));

  float mn = 3.4e38f;
#pragma unroll 16
  for (int k = 0; k < TC; ++k) mn = fminf(mn, ws[(size_t)k * TOTQ + g]);

  // clamp-after-min == min-of-clamps (clamp is monotone); matches ref's
  // maximum(d2, 0) before the min.
  float sum = fmaxf(mn + q2, 0.0f);

#pragma unroll
  for (int off = 32; off > 0; off >>= 1) sum += __shfl_down(sum, off);
  __shared__ float red[4];
  const int lane = threadIdx.x & 63;
  const int wave = threadIdx.x >> 6;
  if (lane == 0) red[wave] = sum;
  __syncthreads();
  if (threadIdx.x == 0) {
    atomicAdd(out, (red[0] + red[1] + red[2] + red[3]) * SCALE);
  }
}

extern "C" void kernel_launch(void* const* d_in, const int* in_sizes, int n_in,
                              void* d_out, int out_size, void* d_ws, size_t ws_size,
                              hipStream_t stream) {
  const float* pred = (const float*)d_in[0];
  const float* gt = (const float*)d_in[1];
  float* out = (float*)d_out;
  float* ws = (float*)d_ws;

  hipMemsetAsync(d_out, 0, sizeof(float), stream);

  if (ws_size >= (size_t)TOTQ * 64 * sizeof(float)) {
    dim3 g1(64, NQC, 4);  // 1024 blocks = 4/CU
    chamfer_nn_kernel<64><<<g1, 256, 0, stream>>>(pred, gt, ws);
    chamfer_reduce_kernel<64><<<TOTQ / 256, 256, 0, stream>>>(pred, gt, ws, out);
  } else {
    dim3 g1(32, NQC, 4);  // 4 MiB ws fallback
    chamfer_nn_kernel<32><<<g1, 256, 0, stream>>>(pred, gt, ws);
    chamfer_reduce_kernel<32><<<TOTQ / 256, 256, 0, stream>>>(pred, gt, ws, out);
  }
}